// Round 10
// baseline (1094.510 us; speedup 1.0000x reference)
//
#include <hip/hip_runtime.h>

#define NN 100000
#define NE 1600000
#define NG 1024
#define NODE_IN 163
#define SLOPE 0.01f
#define NBUK 391      // ceil(100000/256)
#define BUKSH 8       // 256 nodes per bucket
#define EPB 8192      // edges per partition block
#define NBLK ((NE + EPB - 1) / EPB)   // 196

// ---------------- CSR build (privatized counting sort; round-4, verified) -------------
__global__ void k_hist(const int* __restrict__ dst, int* __restrict__ bh, int E) {
  __shared__ int h[NBUK];
  for (int i = threadIdx.x; i < NBUK; i += 256) h[i] = 0;
  __syncthreads();
  int beg = blockIdx.x * EPB, end = min(E, beg + EPB);
  for (int e = beg + threadIdx.x; e < end; e += 256) atomicAdd(&h[dst[e] >> BUKSH], 1);
  __syncthreads();
  for (int i = threadIdx.x; i < NBUK; i += 256) bh[blockIdx.x * NBUK + i] = h[i];
}

__global__ void k_bucket_scan(int* __restrict__ bh, int* __restrict__ btot) {
  __shared__ int s[256];
  int bucket = blockIdx.x, tid = threadIdx.x;
  int v = (tid < NBLK) ? bh[tid * NBUK + bucket] : 0;
  s[tid] = v;
  __syncthreads();
  for (int off = 1; off < 256; off <<= 1) {
    int t = (tid >= off) ? s[tid - off] : 0;
    __syncthreads();
    s[tid] += t;
    __syncthreads();
  }
  if (tid < NBLK) bh[tid * NBUK + bucket] = s[tid] - v;
  if (tid == 255) btot[bucket] = s[255];
}

__global__ void k_btot_scan(const int* __restrict__ btot, int* __restrict__ boffs, int E) {
  __shared__ int s[512];
  int tid = threadIdx.x;
  int v = (tid < NBUK) ? btot[tid] : 0;
  s[tid] = v;
  __syncthreads();
  for (int off = 1; off < 512; off <<= 1) {
    int t = (tid >= off) ? s[tid - off] : 0;
    __syncthreads();
    s[tid] += t;
    __syncthreads();
  }
  if (tid < NBUK) boffs[tid] = s[tid] - v;
  if (tid == 0) boffs[NBUK] = E;
}

__global__ void k_scatter(const int* __restrict__ src, const int* __restrict__ dst,
                          const int* __restrict__ bh, const int* __restrict__ boffs,
                          unsigned* __restrict__ bedge, int E) {
  __shared__ int cur[NBUK];
  for (int i = threadIdx.x; i < NBUK; i += 256)
    cur[i] = boffs[i] + bh[blockIdx.x * NBUK + i];
  __syncthreads();
  int beg = blockIdx.x * EPB, end = min(E, beg + EPB);
  for (int e = beg + threadIdx.x; e < end; e += 256) {
    int d = dst[e];
    int pos = atomicAdd(&cur[d >> BUKSH], 1);
    bedge[pos] = (unsigned)src[e] | ((unsigned)(d & 255) << 17);
  }
}

__global__ void k_b2csr(const unsigned* __restrict__ bedge, const int* __restrict__ boffs,
                        int* __restrict__ offs, float* __restrict__ dis,
                        int* __restrict__ csr, int N) {
  __shared__ int lcnt[256];
  __shared__ int s[256];
  __shared__ int lcur[256];
  int b = blockIdx.x, tid = threadIdx.x;
  int beg = boffs[b], end = boffs[b + 1];
  lcnt[tid] = 0;
  __syncthreads();
  for (int e = beg + tid; e < end; e += 256) atomicAdd(&lcnt[bedge[e] >> 17], 1);
  __syncthreads();
  int v = lcnt[tid];
  s[tid] = v;
  __syncthreads();
  for (int off = 1; off < 256; off <<= 1) {
    int t = (tid >= off) ? s[tid - off] : 0;
    __syncthreads();
    s[tid] += t;
    __syncthreads();
  }
  int o = s[tid] - v;
  int node = (b << BUKSH) + tid;
  if (node <= N) offs[node] = beg + o;
  if (node < N) dis[node] = rsqrtf((float)(v + 1));
  lcur[tid] = o;
  __syncthreads();
  for (int e = beg + tid; e < end; e += 256) {
    unsigned w = bedge[e];
    int p = atomicAdd(&lcur[w >> 17], 1);
    csr[beg + p] = (int)(w & 0x1FFFFu);
  }
}

// ---------------- GEMM: 128-row tile, 8x4 microtile, k-major X in LDS -----------------
// Wave = 32 rows x 64 cols; lane: rows xoff..xoff+7 (contig), cols c0..c0+3.
// Register budget sized TO the 128-VGPR tier (16 waves/CU): acc 32 + stage 12 +
// operands 12 + addressing ~25 ~= 90 < 128. Round-9 was 132 VGPR -> 8 waves/CU
// (the >128 cliff, m69) -> 1.5 dispatch generations + no latency hiding.
// K-tail (163): last chunk loads {x160,x161,x162,0} via uniform branch; LDS k-slots
// >=163 hold garbage but W's k-rows >=163 are zeroed -> product 0. Max X index
// read = 99999*163+162 = last element (no OOB). Staging rows clamped to N-1.
template<int K>
__launch_bounds__(256, 4)
__global__ void k_gemm(const float* __restrict__ X, const float* __restrict__ W,
                       const float* __restrict__ disv, float* __restrict__ Y, int N) {
  constexpr int KC = (K + 15) >> 4;
  __shared__ float sX[2][16 * 128];
  __shared__ float sW[2][16 * 64];
  const int tid = threadIdx.x;
  const int lane = tid & 63, wv = tid >> 6;
  const int xoff = wv * 32 + ((lane >> 4) << 3);   // row within 128-row tile
  const int c0 = (lane & 15) << 2;                 // col
  const long gbase = (long)blockIdx.x * 128;
  const int srow = tid >> 1, koff = (tid & 1) << 3; // X staging: row, k-offset
  const int wk = tid >> 4, wc = (tid & 15) << 2;    // W staging slot

  long gr = gbase + srow;
  if (K == NODE_IN) gr = (gr < (long)N) ? gr : (long)(N - 1);  // input X is exact-sized
  const float* xr = X + gr * K + koff;              // K==64: workspace has NPAD rows

  float4 rx0, rx1, rw;

  auto loadX = [&](int c) {
    if (K == NODE_IN && c == KC - 1) {              // uniform per-block tail branch
      rx1 = make_float4(0.f, 0.f, 0.f, 0.f);
      if (koff == 0) rx0 = make_float4(xr[160], xr[161], xr[162], 0.f);
      else           rx0 = make_float4(0.f, 0.f, 0.f, 0.f);
    } else {
      rx0 = *(const float4*)(xr + c * 16);
      rx1 = *(const float4*)(xr + c * 16 + 4);
    }
  };
  auto loadW = [&](int c) {
    int gk = c * 16 + wk;
    if (K % 16 == 0) {
      rw = *(const float4*)(W + (size_t)gk * 64 + wc);
    } else {
      rw = (gk < K) ? *(const float4*)(W + (size_t)gk * 64 + wc)
                    : make_float4(0.f, 0.f, 0.f, 0.f);
    }
  };
  auto writeLDS = [&](int b) {
    float* xb = sX[b];
    xb[(koff + 0) * 128 + srow] = rx0.x;   // k-major transpose; 2-way alias (free)
    xb[(koff + 1) * 128 + srow] = rx0.y;
    xb[(koff + 2) * 128 + srow] = rx0.z;
    xb[(koff + 3) * 128 + srow] = rx0.w;
    xb[(koff + 4) * 128 + srow] = rx1.x;
    xb[(koff + 5) * 128 + srow] = rx1.y;
    xb[(koff + 6) * 128 + srow] = rx1.z;
    xb[(koff + 7) * 128 + srow] = rx1.w;
    *(float4*)(sW[b] + wk * 64 + wc) = rw;
  };

  loadX(0); loadW(0); writeLDS(0);

  float acc[32];
  #pragma unroll
  for (int i = 0; i < 32; ++i) acc[i] = 0.f;

  #pragma unroll 1
  for (int c = 0; c < KC; ++c) {
    if (c + 1 < KC) { loadX(c + 1); loadW(c + 1); }   // issue early (T14)
    __syncthreads();
    const float* sXc = sX[c & 1];
    const float* sWc = sW[c & 1];
    #pragma unroll
    for (int k = 0; k < 16; ++k) {
      float4 xa = *(const float4*)(sXc + k * 128 + xoff);      // 16-lane broadcast
      float4 xb = *(const float4*)(sXc + k * 128 + xoff + 4);
      float4 wr = *(const float4*)(sWc + k * 64 + c0);         // 2-way alias (free)
      float xr8[8] = {xa.x, xa.y, xa.z, xa.w, xb.x, xb.y, xb.z, xb.w};
      #pragma unroll
      for (int r = 0; r < 8; ++r) {
        acc[r * 4 + 0] += xr8[r] * wr.x;
        acc[r * 4 + 1] += xr8[r] * wr.y;
        acc[r * 4 + 2] += xr8[r] * wr.z;
        acc[r * 4 + 3] += xr8[r] * wr.w;
      }
    }
    if (c + 1 < KC) writeLDS((c + 1) & 1);            // write late (other buffer)
  }

  #pragma unroll
  for (int r = 0; r < 8; ++r) {
    long row = gbase + xoff + r;
    if (row < N) {
      float d = disv[row];
      *(float4*)(Y + row * 64 + c0) =
          make_float4(acc[r*4+0]*d, acc[r*4+1]*d, acc[r*4+2]*d, acc[r*4+3]*d);
    }
  }
}

// One wave per node: Hout[i] = lrelu( (Hps[i] + sum_{e->i} Hps[src]) * dis[i] + b )
__launch_bounds__(256)
__global__ void k_agg(const float* __restrict__ Hps, const int* __restrict__ offs,
                      const int* __restrict__ csr, const float* __restrict__ dis,
                      const float* __restrict__ bias, float* __restrict__ Hout, int N) {
  int node = blockIdx.x * 4 + (threadIdx.x >> 6);
  if (node >= N) return;
  int lane = threadIdx.x & 63;
  int beg = offs[node], end = offs[node + 1];
  float acc = Hps[(size_t)node * 64 + lane];
  int e = beg;
  for (; e + 8 <= end; e += 8) {
    int s0 = csr[e + 0], s1 = csr[e + 1], s2 = csr[e + 2], s3 = csr[e + 3];
    int s4 = csr[e + 4], s5 = csr[e + 5], s6 = csr[e + 6], s7 = csr[e + 7];
    acc += Hps[(size_t)s0 * 64 + lane];
    acc += Hps[(size_t)s1 * 64 + lane];
    acc += Hps[(size_t)s2 * 64 + lane];
    acc += Hps[(size_t)s3 * 64 + lane];
    acc += Hps[(size_t)s4 * 64 + lane];
    acc += Hps[(size_t)s5 * 64 + lane];
    acc += Hps[(size_t)s6 * 64 + lane];
    acc += Hps[(size_t)s7 * 64 + lane];
  }
  for (; e + 4 <= end; e += 4) {
    int s0 = csr[e], s1 = csr[e + 1], s2 = csr[e + 2], s3 = csr[e + 3];
    acc += Hps[(size_t)s0 * 64 + lane];
    acc += Hps[(size_t)s1 * 64 + lane];
    acc += Hps[(size_t)s2 * 64 + lane];
    acc += Hps[(size_t)s3 * 64 + lane];
  }
  for (; e < end; ++e) acc += Hps[(size_t)csr[e] * 64 + lane];
  acc = acc * dis[node] + bias[lane];
  Hout[(size_t)node * 64 + lane] = (acc > 0.f) ? acc : SLOPE * acc;
}

// One wave per graph: mean-pool + fc1 + lrelu + fc2
__launch_bounds__(64)
__global__ void k_pool(const float* __restrict__ H, const int* __restrict__ batch,
                       const float* __restrict__ f1W, const float* __restrict__ f1b,
                       const float* __restrict__ f2W, const float* __restrict__ f2b,
                       float* __restrict__ out, int N) {
  int g = blockIdx.x;
  int lane = threadIdx.x;
  int lo = 0, hi = N;
  while (lo < hi) { int m = (lo + hi) >> 1; if (batch[m] < g) lo = m + 1; else hi = m; }
  int beg = lo;
  hi = N;
  while (lo < hi) { int m = (lo + hi) >> 1; if (batch[m] < g + 1) lo = m + 1; else hi = m; }
  int end = lo;
  float acc = 0.f;
  for (int r = beg; r < end; ++r) acc += H[(size_t)r * 64 + lane];
  float c = (float)(end - beg);
  acc /= (c < 1.f ? 1.f : c);
  __shared__ float p[64];
  p[lane] = acc;
  __syncthreads();
  float q = f1b[lane];
  #pragma unroll
  for (int k = 0; k < 64; ++k) q += p[k] * f1W[k * 64 + lane];
  q = (q > 0.f) ? q : SLOPE * q;
  float v = q * f2W[lane];
  #pragma unroll
  for (int off = 32; off > 0; off >>= 1) v += __shfl_down(v, off, 64);
  if (lane == 0) out[g] = v + f2b[0];
}

extern "C" void kernel_launch(void* const* d_in, const int* in_sizes, int n_in,
                              void* d_out, int out_size, void* d_ws, size_t ws_size,
                              hipStream_t stream) {
  const float* x    = (const float*)d_in[0];
  const int*  eidx  = (const int*)d_in[1];
  const int*  batch = (const int*)d_in[2];
  const float* W0 = (const float*)d_in[3];
  const float* b0 = (const float*)d_in[4];
  const float* W1 = (const float*)d_in[5];
  const float* b1 = (const float*)d_in[6];
  const float* W2 = (const float*)d_in[7];
  const float* b2 = (const float*)d_in[8];
  const float* f1W = (const float*)d_in[9];
  const float* f1b = (const float*)d_in[10];
  const float* f2W = (const float*)d_in[11];
  const float* f2b = (const float*)d_in[12];
  float* out = (float*)d_out;

  const int N = NN, E = NE;
  const int* src  = eidx;
  const int* dstp = eidx + E;

  const size_t NPAD = 100096;
  char* w = (char*)d_ws;
  float* bufA  = (float*)w; w += NPAD * 64 * 4;   // bedge aliases bufA (dead until gemm0)
  float* bufB  = (float*)w; w += NPAD * 64 * 4;
  int*   csr   = (int*)w;   w += (size_t)E * 4;
  int*   offs  = (int*)w;   w += (size_t)(N + 4) * 4;
  float* dis   = (float*)w; w += (size_t)N * 4;
  int*   bh    = (int*)w;   w += (size_t)NBLK * NBUK * 4;
  int*   btot  = (int*)w;   w += (NBUK + 1) * 4;
  int*   boffs = (int*)w;   w += (NBUK + 1) * 4;
  unsigned* bedge = (unsigned*)bufA;

  k_hist<<<NBLK, 256, 0, stream>>>(dstp, bh, E);
  k_bucket_scan<<<NBUK, 256, 0, stream>>>(bh, btot);
  k_btot_scan<<<1, 512, 0, stream>>>(btot, boffs, E);
  k_scatter<<<NBLK, 256, 0, stream>>>(src, dstp, bh, boffs, bedge, E);
  k_b2csr<<<NBUK, 256, 0, stream>>>(bedge, boffs, offs, dis, csr, N);

  const int NTB = (N + 127) / 128;   // 782
  k_gemm<NODE_IN><<<NTB, 256, 0, stream>>>(x, W0, dis, bufA, N);
  k_agg<<<(N + 3) / 4, 256, 0, stream>>>(bufA, offs, csr, dis, b0, bufB, N);
  k_gemm<64><<<NTB, 256, 0, stream>>>(bufB, W1, dis, bufA, N);
  k_agg<<<(N + 3) / 4, 256, 0, stream>>>(bufA, offs, csr, dis, b1, bufB, N);
  k_gemm<64><<<NTB, 256, 0, stream>>>(bufB, W2, dis, bufA, N);
  k_agg<<<(N + 3) / 4, 256, 0, stream>>>(bufA, offs, csr, dis, b2, bufB, N);
  k_pool<<<NG, 64, 0, stream>>>(bufB, batch, f1W, f1b, f2W, f2b, out, N);
}

// Round 11
// 415.090 us; speedup vs baseline: 2.6368x; 2.6368x over previous
//
#include <hip/hip_runtime.h>

#define NN 100000
#define NE 1600000
#define NG 1024
#define NODE_IN 163
#define SLOPE 0.01f
#define NBUK 391      // ceil(100000/256)
#define BUKSH 8       // 256 nodes per bucket
#define EPB 8192      // edges per partition block
#define NBLK ((NE + EPB - 1) / EPB)   // 196

// ---------------- CSR build (privatized counting sort; round-4, verified) -------------
__global__ void k_hist(const int* __restrict__ dst, int* __restrict__ bh, int E) {
  __shared__ int h[NBUK];
  for (int i = threadIdx.x; i < NBUK; i += 256) h[i] = 0;
  __syncthreads();
  int beg = blockIdx.x * EPB, end = min(E, beg + EPB);
  for (int e = beg + threadIdx.x; e < end; e += 256) atomicAdd(&h[dst[e] >> BUKSH], 1);
  __syncthreads();
  for (int i = threadIdx.x; i < NBUK; i += 256) bh[blockIdx.x * NBUK + i] = h[i];
}

__global__ void k_bucket_scan(int* __restrict__ bh, int* __restrict__ btot) {
  __shared__ int s[256];
  int bucket = blockIdx.x, tid = threadIdx.x;
  int v = (tid < NBLK) ? bh[tid * NBUK + bucket] : 0;
  s[tid] = v;
  __syncthreads();
  for (int off = 1; off < 256; off <<= 1) {
    int t = (tid >= off) ? s[tid - off] : 0;
    __syncthreads();
    s[tid] += t;
    __syncthreads();
  }
  if (tid < NBLK) bh[tid * NBUK + bucket] = s[tid] - v;
  if (tid == 255) btot[bucket] = s[255];
}

__global__ void k_btot_scan(const int* __restrict__ btot, int* __restrict__ boffs, int E) {
  __shared__ int s[512];
  int tid = threadIdx.x;
  int v = (tid < NBUK) ? btot[tid] : 0;
  s[tid] = v;
  __syncthreads();
  for (int off = 1; off < 512; off <<= 1) {
    int t = (tid >= off) ? s[tid - off] : 0;
    __syncthreads();
    s[tid] += t;
    __syncthreads();
  }
  if (tid < NBUK) boffs[tid] = s[tid] - v;
  if (tid == 0) boffs[NBUK] = E;
}

__global__ void k_scatter(const int* __restrict__ src, const int* __restrict__ dst,
                          const int* __restrict__ bh, const int* __restrict__ boffs,
                          unsigned* __restrict__ bedge, int E) {
  __shared__ int cur[NBUK];
  for (int i = threadIdx.x; i < NBUK; i += 256)
    cur[i] = boffs[i] + bh[blockIdx.x * NBUK + i];
  __syncthreads();
  int beg = blockIdx.x * EPB, end = min(E, beg + EPB);
  for (int e = beg + threadIdx.x; e < end; e += 256) {
    int d = dst[e];
    int pos = atomicAdd(&cur[d >> BUKSH], 1);
    bedge[pos] = (unsigned)src[e] | ((unsigned)(d & 255) << 17);
  }
}

__global__ void k_b2csr(const unsigned* __restrict__ bedge, const int* __restrict__ boffs,
                        int* __restrict__ offs, float* __restrict__ dis,
                        int* __restrict__ csr, int N) {
  __shared__ int lcnt[256];
  __shared__ int s[256];
  __shared__ int lcur[256];
  int b = blockIdx.x, tid = threadIdx.x;
  int beg = boffs[b], end = boffs[b + 1];
  lcnt[tid] = 0;
  __syncthreads();
  for (int e = beg + tid; e < end; e += 256) atomicAdd(&lcnt[bedge[e] >> 17], 1);
  __syncthreads();
  int v = lcnt[tid];
  s[tid] = v;
  __syncthreads();
  for (int off = 1; off < 256; off <<= 1) {
    int t = (tid >= off) ? s[tid - off] : 0;
    __syncthreads();
    s[tid] += t;
    __syncthreads();
  }
  int o = s[tid] - v;
  int node = (b << BUKSH) + tid;
  if (node <= N) offs[node] = beg + o;
  if (node < N) dis[node] = rsqrtf((float)(v + 1));
  lcur[tid] = o;
  __syncthreads();
  for (int e = beg + tid; e < end; e += 256) {
    unsigned w = bedge[e];
    int p = atomicAdd(&lcur[w >> 17], 1);
    csr[beg + p] = (int)(w & 0x1FFFFu);
  }
}

// ---------------- GEMM: 128-row tile, 8x4 microtile, k-major X in LDS -----------------
// Wave = 32 rows x 64 cols; lane: rows xoff..xoff+7 (contig), cols c0..c0+3.
// NO occupancy hint: every hinted build (rounds 7/8/10) spilled acc to scratch
// (0.5-1.9 GB of HBM spill traffic); the only clean build was hint-free (round 9,
// 132 VGPR). This version shaves ~10 regs off round 9 (uniform tail branch, no
// per-element masks, 32-bit epilogue row math) hoping to land <=128 (occupancy
// cliff, m69: waves/CU halves above 128).
template<int K>
__launch_bounds__(256)
__global__ void k_gemm(const float* __restrict__ X, const float* __restrict__ W,
                       const float* __restrict__ disv, float* __restrict__ Y, int N) {
  constexpr int KC = (K + 15) >> 4;
  __shared__ float sX[2][16 * 128];
  __shared__ float sW[2][16 * 64];
  const int tid = threadIdx.x;
  const int lane = tid & 63, wv = tid >> 6;
  const int xoff = wv * 32 + ((lane >> 4) << 3);   // row within 128-row tile
  const int c0 = (lane & 15) << 2;                 // col
  const int gbase = blockIdx.x << 7;               // tile base row (fits int)
  const int srow = tid >> 1, koff = (tid & 1) << 3; // X staging: row, k-offset
  const int wk = tid >> 4, wc = (tid & 15) << 2;    // W staging slot

  int gr = gbase + srow;
  if (K == NODE_IN) gr = (gr < N) ? gr : (N - 1);   // input X is exact-sized
  const float* xr = X + (size_t)gr * K + koff;      // K==64: workspace has NPAD rows

  float4 rx0, rx1, rw;

  auto loadX = [&](int c) {
    if (K == NODE_IN && c == KC - 1) {              // uniform per-block tail branch
      rx1 = make_float4(0.f, 0.f, 0.f, 0.f);
      if (koff == 0) rx0 = make_float4(xr[160], xr[161], xr[162], 0.f);
      else           rx0 = make_float4(0.f, 0.f, 0.f, 0.f);
    } else {
      rx0 = *(const float4*)(xr + c * 16);
      rx1 = *(const float4*)(xr + c * 16 + 4);
    }
  };
  auto loadW = [&](int c) {
    int gk = c * 16 + wk;
    if (K % 16 == 0) {
      rw = *(const float4*)(W + (size_t)gk * 64 + wc);
    } else {
      rw = (gk < K) ? *(const float4*)(W + (size_t)gk * 64 + wc)
                    : make_float4(0.f, 0.f, 0.f, 0.f);
    }
  };
  auto writeLDS = [&](int b) {
    float* xb = sX[b];
    xb[(koff + 0) * 128 + srow] = rx0.x;   // k-major transpose; 2-way alias (free)
    xb[(koff + 1) * 128 + srow] = rx0.y;
    xb[(koff + 2) * 128 + srow] = rx0.z;
    xb[(koff + 3) * 128 + srow] = rx0.w;
    xb[(koff + 4) * 128 + srow] = rx1.x;
    xb[(koff + 5) * 128 + srow] = rx1.y;
    xb[(koff + 6) * 128 + srow] = rx1.z;
    xb[(koff + 7) * 128 + srow] = rx1.w;
    *(float4*)(sW[b] + wk * 64 + wc) = rw;
  };

  loadX(0); loadW(0); writeLDS(0);

  float acc[32];
  #pragma unroll
  for (int i = 0; i < 32; ++i) acc[i] = 0.f;

  #pragma unroll 1
  for (int c = 0; c < KC; ++c) {
    if (c + 1 < KC) { loadX(c + 1); loadW(c + 1); }   // issue early (T14)
    __syncthreads();
    const float* sXc = sX[c & 1];
    const float* sWc = sW[c & 1];
    #pragma unroll
    for (int k = 0; k < 16; ++k) {
      float4 xa = *(const float4*)(sXc + k * 128 + xoff);      // 16-lane broadcast
      float4 xb = *(const float4*)(sXc + k * 128 + xoff + 4);
      float4 wr = *(const float4*)(sWc + k * 64 + c0);         // 2-way alias (free)
      float xr8[8] = {xa.x, xa.y, xa.z, xa.w, xb.x, xb.y, xb.z, xb.w};
      #pragma unroll
      for (int r = 0; r < 8; ++r) {
        acc[r * 4 + 0] += xr8[r] * wr.x;
        acc[r * 4 + 1] += xr8[r] * wr.y;
        acc[r * 4 + 2] += xr8[r] * wr.z;
        acc[r * 4 + 3] += xr8[r] * wr.w;
      }
    }
    if (c + 1 < KC) writeLDS((c + 1) & 1);            // write late (other buffer)
  }

  float* yb = Y + (size_t)(gbase + xoff) * 64 + c0;   // single 64-bit base; rows in int
  #pragma unroll
  for (int r = 0; r < 8; ++r) {
    int row = gbase + xoff + r;
    if (row < N) {
      float d = disv[row];
      *(float4*)(yb + (size_t)r * 64) =
          make_float4(acc[r*4+0]*d, acc[r*4+1]*d, acc[r*4+2]*d, acc[r*4+3]*d);
    }
  }
}

// One wave per node: Hout[i] = lrelu( (Hps[i] + sum_{e->i} Hps[src]) * dis[i] + b )
__launch_bounds__(256)
__global__ void k_agg(const float* __restrict__ Hps, const int* __restrict__ offs,
                      const int* __restrict__ csr, const float* __restrict__ dis,
                      const float* __restrict__ bias, float* __restrict__ Hout, int N) {
  int node = blockIdx.x * 4 + (threadIdx.x >> 6);
  if (node >= N) return;
  int lane = threadIdx.x & 63;
  int beg = offs[node], end = offs[node + 1];
  float acc = Hps[(size_t)node * 64 + lane];
  int e = beg;
  for (; e + 8 <= end; e += 8) {
    int s0 = csr[e + 0], s1 = csr[e + 1], s2 = csr[e + 2], s3 = csr[e + 3];
    int s4 = csr[e + 4], s5 = csr[e + 5], s6 = csr[e + 6], s7 = csr[e + 7];
    acc += Hps[(size_t)s0 * 64 + lane];
    acc += Hps[(size_t)s1 * 64 + lane];
    acc += Hps[(size_t)s2 * 64 + lane];
    acc += Hps[(size_t)s3 * 64 + lane];
    acc += Hps[(size_t)s4 * 64 + lane];
    acc += Hps[(size_t)s5 * 64 + lane];
    acc += Hps[(size_t)s6 * 64 + lane];
    acc += Hps[(size_t)s7 * 64 + lane];
  }
  for (; e + 4 <= end; e += 4) {
    int s0 = csr[e], s1 = csr[e + 1], s2 = csr[e + 2], s3 = csr[e + 3];
    acc += Hps[(size_t)s0 * 64 + lane];
    acc += Hps[(size_t)s1 * 64 + lane];
    acc += Hps[(size_t)s2 * 64 + lane];
    acc += Hps[(size_t)s3 * 64 + lane];
  }
  for (; e < end; ++e) acc += Hps[(size_t)csr[e] * 64 + lane];
  acc = acc * dis[node] + bias[lane];
  Hout[(size_t)node * 64 + lane] = (acc > 0.f) ? acc : SLOPE * acc;
}

// One wave per graph: mean-pool + fc1 + lrelu + fc2
__launch_bounds__(64)
__global__ void k_pool(const float* __restrict__ H, const int* __restrict__ batch,
                       const float* __restrict__ f1W, const float* __restrict__ f1b,
                       const float* __restrict__ f2W, const float* __restrict__ f2b,
                       float* __restrict__ out, int N) {
  int g = blockIdx.x;
  int lane = threadIdx.x;
  int lo = 0, hi = N;
  while (lo < hi) { int m = (lo + hi) >> 1; if (batch[m] < g) lo = m + 1; else hi = m; }
  int beg = lo;
  hi = N;
  while (lo < hi) { int m = (lo + hi) >> 1; if (batch[m] < g + 1) lo = m + 1; else hi = m; }
  int end = lo;
  float acc = 0.f;
  for (int r = beg; r < end; ++r) acc += H[(size_t)r * 64 + lane];
  float c = (float)(end - beg);
  acc /= (c < 1.f ? 1.f : c);
  __shared__ float p[64];
  p[lane] = acc;
  __syncthreads();
  float q = f1b[lane];
  #pragma unroll
  for (int k = 0; k < 64; ++k) q += p[k] * f1W[k * 64 + lane];
  q = (q > 0.f) ? q : SLOPE * q;
  float v = q * f2W[lane];
  #pragma unroll
  for (int off = 32; off > 0; off >>= 1) v += __shfl_down(v, off, 64);
  if (lane == 0) out[g] = v + f2b[0];
}

extern "C" void kernel_launch(void* const* d_in, const int* in_sizes, int n_in,
                              void* d_out, int out_size, void* d_ws, size_t ws_size,
                              hipStream_t stream) {
  const float* x    = (const float*)d_in[0];
  const int*  eidx  = (const int*)d_in[1];
  const int*  batch = (const int*)d_in[2];
  const float* W0 = (const float*)d_in[3];
  const float* b0 = (const float*)d_in[4];
  const float* W1 = (const float*)d_in[5];
  const float* b1 = (const float*)d_in[6];
  const float* W2 = (const float*)d_in[7];
  const float* b2 = (const float*)d_in[8];
  const float* f1W = (const float*)d_in[9];
  const float* f1b = (const float*)d_in[10];
  const float* f2W = (const float*)d_in[11];
  const float* f2b = (const float*)d_in[12];
  float* out = (float*)d_out;

  const int N = NN, E = NE;
  const int* src  = eidx;
  const int* dstp = eidx + E;

  const size_t NPAD = 100096;
  char* w = (char*)d_ws;
  float* bufA  = (float*)w; w += NPAD * 64 * 4;   // bedge aliases bufA (dead until gemm0)
  float* bufB  = (float*)w; w += NPAD * 64 * 4;
  int*   csr   = (int*)w;   w += (size_t)E * 4;
  int*   offs  = (int*)w;   w += (size_t)(N + 4) * 4;
  float* dis   = (float*)w; w += (size_t)N * 4;
  int*   bh    = (int*)w;   w += (size_t)NBLK * NBUK * 4;
  int*   btot  = (int*)w;   w += (NBUK + 1) * 4;
  int*   boffs = (int*)w;   w += (NBUK + 1) * 4;
  unsigned* bedge = (unsigned*)bufA;

  k_hist<<<NBLK, 256, 0, stream>>>(dstp, bh, E);
  k_bucket_scan<<<NBUK, 256, 0, stream>>>(bh, btot);
  k_btot_scan<<<1, 512, 0, stream>>>(btot, boffs, E);
  k_scatter<<<NBLK, 256, 0, stream>>>(src, dstp, bh, boffs, bedge, E);
  k_b2csr<<<NBUK, 256, 0, stream>>>(bedge, boffs, offs, dis, csr, N);

  const int NTB = (N + 127) / 128;   // 782
  k_gemm<NODE_IN><<<NTB, 256, 0, stream>>>(x, W0, dis, bufA, N);
  k_agg<<<(N + 3) / 4, 256, 0, stream>>>(bufA, offs, csr, dis, b0, bufB, N);
  k_gemm<64><<<NTB, 256, 0, stream>>>(bufB, W1, dis, bufA, N);
  k_agg<<<(N + 3) / 4, 256, 0, stream>>>(bufA, offs, csr, dis, b1, bufB, N);
  k_gemm<64><<<NTB, 256, 0, stream>>>(bufB, W2, dis, bufA, N);
  k_agg<<<(N + 3) / 4, 256, 0, stream>>>(bufA, offs, csr, dis, b2, bufB, N);
  k_pool<<<NG, 64, 0, stream>>>(bufB, batch, f1W, f1b, f2W, f2b, out, N);
}